// Round 11
// baseline (51.362 us; speedup 1.0000x reference)
//
#include <hip/hip_runtime.h>
#include <hip/hip_bf16.h>

#define N_IN 4096
#define N_OUT 14336
#define TOPK 1228            // int(4096 * 0.3)

typedef float f32x4 __attribute__((ext_vector_type(4)));

// ---------------------------------------------------------------------------
// Kernel A (proven, unchanged since round 7): threshold = TOPK-th largest |x|
// via 4-pass radix select on the positive-float bit pattern. Single block,
// 1024 threads. Ballot-aggregated histogram + single-wave shfl suffix-scan.
// Writes x_masked (non-topk zeroed) to workspace.
// ---------------------------------------------------------------------------
__global__ __launch_bounds__(1024) void topk_mask_kernel(
    const float* __restrict__ x, float* __restrict__ x_masked) {
  __shared__ unsigned int s_abs[N_IN];                  // 16 KB
  __shared__ unsigned int s_hist[256];
  __shared__ unsigned int s_pk[4];                      // prefix, krem, eqc
  __shared__ unsigned long long s_cmask[N_IN / 64];     // tie path
  __shared__ unsigned int s_cbase[N_IN / 64];

  const int tid = threadIdx.x;
  const int lane = tid & 63;

#pragma unroll
  for (int it = 0; it < N_IN / 1024; ++it) {
    const int i = it * 1024 + tid;
    s_abs[i] = __float_as_uint(x[i]) & 0x7fffffffu;
  }
  if (tid == 0) { s_pk[0] = 0u; s_pk[1] = TOPK; }
  __syncthreads();

  // Radix select, MSB byte -> LSB byte.
  for (int pass = 3; pass >= 0; --pass) {
    const unsigned int prefix = s_pk[0];
    const unsigned int krem = s_pk[1];
    if (tid < 256) s_hist[tid] = 0u;
    __syncthreads();

    const int shift = pass * 8;
    const unsigned int maskAbove =
        (pass == 3) ? 0u : (0xFFFFFFFFu << (shift + 8));

    // Ballot-aggregated histogram: one atomic per distinct bucket per wave.
#pragma unroll
    for (int it = 0; it < N_IN / 1024; ++it) {
      const int i = it * 1024 + tid;
      const unsigned int b = s_abs[i];
      const bool active = ((b & maskAbove) == prefix);
      const unsigned int bucket = (b >> shift) & 0xFFu;
      unsigned long long m = __ballot(active);
#pragma unroll
      for (int bit = 0; bit < 8; ++bit) {
        const unsigned long long vote =
            __ballot(active && ((bucket >> bit) & 1u));
        m &= ((bucket >> bit) & 1u) ? vote : ~vote;
      }
      if (active) {
        const int leader = __ffsll((unsigned long long)m) - 1;
        if (lane == leader)
          atomicAdd(&s_hist[bucket], (unsigned int)__popcll(m));
      }
    }
    __syncthreads();

    // Wave 0: 4 bins/lane + shfl suffix-scan; unique winner updates s_pk.
    if (tid < 64) {
      const unsigned int h0 = s_hist[tid * 4 + 0];
      const unsigned int h1 = s_hist[tid * 4 + 1];
      const unsigned int h2 = s_hist[tid * 4 + 2];
      const unsigned int h3 = s_hist[tid * 4 + 3];
      const unsigned int s = h0 + h1 + h2 + h3;
      unsigned int inc = s;
#pragma unroll
      for (int off = 1; off < 64; off <<= 1) {
        const unsigned int v = __shfl_down(inc, off, 64);
        if (tid + off < 64) inc += v;
      }
      const unsigned int U = inc - s;  // sum over lanes > tid
      const unsigned int C3 = U + h3;
      const unsigned int C2 = C3 + h2;
      const unsigned int C1 = C2 + h1;
      const unsigned int C0 = C1 + h0;
      const unsigned int Carr[4] = {C0, C1, C2, C3};
      const unsigned int Sarr[4] = {C1, C2, C3, U};
      const unsigned int hv[4] = {h0, h1, h2, h3};
#pragma unroll
      for (int j = 0; j < 4; ++j) {
        if (Sarr[j] < krem && krem <= Carr[j]) {
          s_pk[0] = prefix | ((unsigned int)(tid * 4 + j) << shift);
          s_pk[1] = krem - Sarr[j];
          s_pk[2] = hv[j];
        }
      }
    }
    __syncthreads();
  }

  const unsigned int t_abs = s_pk[0];  // bits of TOPK-th largest |x|
  const unsigned int need = s_pk[1];   // # of ==t_abs elems to take (>=1)
  const unsigned int eqc = s_pk[2];    // total # of elems ==t_abs

  if (eqc == need) {  // fast path: no tie ranking needed (overwhelming case)
#pragma unroll
    for (int it = 0; it < N_IN / 1024; ++it) {
      const int i = it * 1024 + tid;
      x_masked[i] = (s_abs[i] >= t_abs) ? x[i] : 0.0f;
    }
  } else {  // exact tie ranking, lowest-index-first (jax.lax.top_k stable)
#pragma unroll
    for (int it = 0; it < N_IN / 1024; ++it) {
      const int i = it * 1024 + tid;
      const bool eq = (s_abs[i] == t_abs);
      const unsigned long long m = __ballot(eq);
      if (lane == 0) s_cmask[i >> 6] = m;
    }
    __syncthreads();
    if (tid < 64) {
      const unsigned int cnt = (unsigned int)__popcll(s_cmask[tid]);
      unsigned int inc = cnt;
#pragma unroll
      for (int off = 1; off < 64; off <<= 1) {
        const unsigned int v = __shfl_up(inc, off, 64);
        if (lane >= off) inc += v;
      }
      s_cbase[tid] = inc - cnt;
    }
    __syncthreads();
#pragma unroll
    for (int it = 0; it < N_IN / 1024; ++it) {
      const int i = it * 1024 + tid;
      const unsigned int b = s_abs[i];
      bool sel = (b > t_abs);
      if (b == t_abs) {
        const unsigned long long below =
            s_cmask[i >> 6] & ((1ull << lane) - 1ull);
        sel = (s_cbase[i >> 6] + (unsigned int)__popcll(below)) < need;
      }
      x_masked[i] = sel ? x[i] : 0.0f;
    }
  }
}

// ---------------------------------------------------------------------------
// Kernel B: out[o] = dot(x_masked, W[o,:]) + bias[o].
// SLAB-LINEAR cooperative block: each block (256 thr) owns a CONTIGUOUS
// 128 KB slab of W (8 rows) and reads it in strict linear address order —
// iteration it covers float4s [it*256, it*256+256) = one 4 KB contiguous
// window per block. Device-wide concurrent stream heads: 1792 (one per
// block), vs 14336 in the per-wave-row layout (R6/R7 both had 14336 —
// R7's "2 rows/wave" kept 2 pointers/wave). Targets DRAM page locality:
// each bank sees ~1 sequential stream instead of ~7 interleaved ones.
// Per thread: row = it/4 (8 accumulators, statically indexed after unroll),
// x chunk = it%4 (only 4 xv registers). Epilogue: wave shfl-reduce ->
// 4x8 partials in LDS -> 8 rows written. Grid 1792 = exactly 7 blocks/CU.
// W loads non-temporal (kept from R10).
// ---------------------------------------------------------------------------
__global__ __launch_bounds__(256) void masked_matvec_kernel(
    const float* __restrict__ xm, const float* __restrict__ W,
    const float* __restrict__ bias, float* __restrict__ out) {
  __shared__ float s_part[4][8];

  const int tid = threadIdx.x;
  const int wave = tid >> 6;
  const int lane = tid & 63;
  const int row0 = blockIdx.x * 8;

  const f32x4* __restrict__ slab4 =
      reinterpret_cast<const f32x4*>(W + (size_t)row0 * N_IN);
  const f32x4* __restrict__ x4 = reinterpret_cast<const f32x4*>(xm);

  // 4 x-float4s per thread: xv[j] pairs with every iteration where it%4==j.
  f32x4 xv[4];
#pragma unroll
  for (int j = 0; j < 4; ++j) xv[j] = x4[j * 256 + tid];

  float acc[8];
#pragma unroll
  for (int r = 0; r < 8; ++r) acc[r] = 0.0f;

  // 32 iterations, fully unrolled: it -> row it/4, x-chunk it%4.
  // Addresses advance linearly: idx = it*256 + tid.
#pragma unroll
  for (int it = 0; it < 32; ++it) {
    const f32x4 w = __builtin_nontemporal_load(&slab4[it * 256 + tid]);
    const f32x4 v = xv[it & 3];
    acc[it >> 2] += w.x * v.x + w.y * v.y + w.z * v.z + w.w * v.w;
  }

  // Wave-level reduction of each accumulator, then cross-wave via LDS.
#pragma unroll
  for (int r = 0; r < 8; ++r) {
#pragma unroll
    for (int off = 32; off >= 1; off >>= 1)
      acc[r] += __shfl_down(acc[r], off, 64);
  }
  if (lane == 0) {
#pragma unroll
    for (int r = 0; r < 8; ++r) s_part[wave][r] = acc[r];
  }
  __syncthreads();

  if (tid < 8) {
    const float sum =
        s_part[0][tid] + s_part[1][tid] + s_part[2][tid] + s_part[3][tid];
    out[row0 + tid] = sum + bias[row0 + tid];
  }
}

extern "C" void kernel_launch(void* const* d_in, const int* in_sizes, int n_in,
                              void* d_out, int out_size, void* d_ws,
                              size_t ws_size, hipStream_t stream) {
  const float* x    = (const float*)d_in[0];   // (1,1,4096) f32
  const float* W    = (const float*)d_in[1];   // (14336,4096) f32
  const float* bias = (const float*)d_in[2];   // (14336,) f32
  float* out = (float*)d_out;                  // (1,1,14336) f32
  float* xm  = (float*)d_ws;                   // 4096 f32 scratch

  topk_mask_kernel<<<1, 1024, 0, stream>>>(x, xm);
  masked_matvec_kernel<<<N_OUT / 8, 256, 0, stream>>>(xm, W, bias, out);
}